// Round 3
// baseline (5001.424 us; speedup 1.0000x reference)
//
#include <hip/hip_runtime.h>
#include <cstdint>

// Cortex reservoir: embed(perm-gather) -> persistent neighbor-synced spiking scan
// -> chunked dense readout GEMM.
// ws layout (~73 MiB):
//   OFF_PERM  : perm int[1024]
//   OFF_FLAG  : progress flags int[64]
//   OFF_VSAVE : V snapshot float[65536] (chunk boundary save/restore)
//   OFF_S     : S ping-pong float[2][65536]
//   OFF_A     : A chunk float[128][131072]
//   OFF_P     : split-K partials float[128][128][128]

namespace {

constexpr int TT = 512;
constexpr int DD = 256;
constexpr int CELLS = DD * DD;              // 65536
constexpr long KTOT = 2L * CELLS;           // 131072
constexpr int TB = 128;                     // time-chunk
constexpr int NCH = TT / TB;                // 4
constexpr int KSLAB = 1024;
constexpr int NSLAB = 128;                  // KTOT / KSLAB

constexpr long OFF_PERM = 0;
constexpr long OFF_FLAG = 4096;
constexpr long OFF_VSAVE = 8192;
constexpr long OFF_S = OFF_VSAVE + (long)CELLS * 4;
constexpr long OFF_A = OFF_S + 2L * CELLS * 4;
constexpr long OFF_P = OFF_A + (long)TB * KTOT * 4;
constexpr long WS_REQUIRED = OFF_P + (long)NSLAB * TB * 128 * 4;  // ~72.8 MiB

__global__ __launch_bounds__(256) void perm_kernel(const float* __restrict__ We,
                                                   int* __restrict__ perm) {
    int idx = blockIdx.x * 256 + threadIdx.x;       // over 1024*1024
    if (We[idx] > 0.5f) perm[idx >> 10] = idx & 1023;
}

__global__ void flags_init(int* __restrict__ flags, int v) {
    if (threadIdx.x < 64) flags[threadIdx.x] = v;
}

// Persistent scan for one 128-step chunk. 64 blocks x 256 threads; block owns 4 rows.
// Neighbor-only sync: block b at step t needs S_{t-1} from blocks b+-1, b+-2 (circular).
__global__ __launch_bounds__(256) void scan_chunk(
    const float* __restrict__ X,
    const int* __restrict__ perm,
    const float* __restrict__ mc,
    const float* __restrict__ mf,
    float* __restrict__ Sst,      // ping-pong [2][CELLS]
    float* __restrict__ Vsave,    // [CELLS]
    float* __restrict__ Achunk,   // [TB][KTOT]
    int* __restrict__ flags,      // [64], init = t0
    int t0)
{
#pragma clang fp contract(off)
    __shared__ float Sld[20][DD];   // rows y0-8 .. y0+11 of S_{t-1}
    __shared__ float C5[4][DD];     // vertical 5-sums
    __shared__ float C9[4][DD];     // vertical dilated 9-sums
    __shared__ float ut[32];        // per-step input drive (32 coarse cells)

    const int tid = threadIdx.x;
    const int b = blockIdx.x;
    const int y0 = b * 4;           // 4-row strip, inside one coarse row
    const int cy = y0 >> 3;
    const int x = tid;
    const int nb0 = (b + 62) & 63, nb1 = (b + 63) & 63;
    const int nb2 = (b + 1) & 63,  nb3 = (b + 2) & 63;

    // V state lives in registers for the whole chunk.
    float V[4];
    if (t0 == 0) {
        V[0] = V[1] = V[2] = V[3] = 0.0f;
    } else {
#pragma unroll
        for (int ry = 0; ry < 4; ++ry) V[ry] = Vsave[(y0 + ry) * DD + x];
    }
    float mfv[4];
#pragma unroll
    for (int ry = 0; ry < 4; ++ry) mfv[ry] = mf[(y0 + ry) * DD + x];

    for (int t = t0; t < t0 + TB; ++t) {
        // 1. wait for neighbors to have published S_{t-1}  (flag == completed steps)
        if (tid == 0) {
            long g0 = 0, g1 = 0, g2 = 0, g3 = 0;
            while (__hip_atomic_load(&flags[nb0], __ATOMIC_RELAXED, __HIP_MEMORY_SCOPE_AGENT) < t && ++g0 < (1L << 24)) {}
            while (__hip_atomic_load(&flags[nb1], __ATOMIC_RELAXED, __HIP_MEMORY_SCOPE_AGENT) < t && ++g1 < (1L << 24)) {}
            while (__hip_atomic_load(&flags[nb2], __ATOMIC_RELAXED, __HIP_MEMORY_SCOPE_AGENT) < t && ++g2 < (1L << 24)) {}
            while (__hip_atomic_load(&flags[nb3], __ATOMIC_RELAXED, __HIP_MEMORY_SCOPE_AGENT) < t && ++g3 < (1L << 24)) {}
            __builtin_amdgcn_fence(__ATOMIC_ACQUIRE, "agent");   // invalidate stale L1/L2
        }
        __syncthreads();

        // 2. input drive for this step (exact: mc in {0,1})
        if (tid < 32) {
            int c = cy * 32 + tid;
            ut[tid] = tanhf(X[(long)t * 1024 + perm[c]] * mc[c]);
        }

        // 3. halo load: 20 rows of S_{t-1} (slot (t+1)&1)
        const float* Sprev = Sst + (long)((t + 1) & 1) * CELLS;
        for (int i = tid; i < 20 * 64; i += 256) {
            int rr = i >> 6;
            int x4 = (i & 63) << 2;
            float4 s = make_float4(0.f, 0.f, 0.f, 0.f);
            if (t > 0) {
                int gy = (y0 - 8 + rr) & 255;
                s = *(const float4*)&Sprev[gy * DD + x4];
            }
            *(float4*)&Sld[rr][x4] = s;
        }
        __syncthreads();

        // 4. vertical sums (exact integer counts in fp32)
#pragma unroll
        for (int ry = 0; ry < 4; ++ry) {
            int r = 8 + ry;
            C5[ry][x] = Sld[r-2][x] + Sld[r-1][x] + Sld[r][x] + Sld[r+1][x] + Sld[r+2][x];
            C9[ry][x] = Sld[r-8][x] + Sld[r-6][x] + Sld[r-4][x] + Sld[r-2][x] + Sld[r][x]
                      + Sld[r+2][x] + Sld[r+4][x] + Sld[r+6][x] + Sld[r+8][x];
        }
        __syncthreads();

        // 5. horizontal sums + V update (V in regs); publish S_t
        float Vn[4], Sn[4];
        const float um = ut[x >> 3];
#pragma unroll
        for (int ry = 0; ry < 4; ++ry) {
            float h5 = C5[ry][(x-2)&255] + C5[ry][(x-1)&255] + C5[ry][x]
                     + C5[ry][(x+1)&255] + C5[ry][(x+2)&255];
            float h9 = C9[ry][(x-8)&255] + C9[ry][(x-6)&255] + C9[ry][(x-4)&255]
                     + C9[ry][(x-2)&255] + C9[ry][x]
                     + C9[ry][(x+2)&255] + C9[ry][(x+4)&255]
                     + C9[ry][(x+6)&255] + C9[ry][(x+8)&255];
            float avg5 = h5 * (1.0f/25.0f);
            float avg9 = h9 * (1.0f/81.0f);
            float lat = avg5 - 0.5f * avg9;          // EXC*avg5 + INH*avg9
            float u = um * mfv[ry];                  // exact: mf in {0,1}
            float V1 = 0.9f * V[ry] + 0.5f * u;      // DECAY*V + SPLIT*x
            float V2 = (V1 >= 0.1f) ? ((V1 + 0.5f * u) + lat) : V1;
            V2 = fminf(V2, 1.0f);
            const bool sp = V2 > 0.75f;
            Vn[ry] = sp ? 0.0f : V2;
            Sn[ry] = sp ? 1.0f : 0.0f;
        }
        float* Scur = Sst + (long)(t & 1) * CELLS;
#pragma unroll
        for (int ry = 0; ry < 4; ++ry) Scur[(y0 + ry) * DD + x] = Sn[ry];

        // 6. publish: make S stores device-visible, then bump flag
        __builtin_amdgcn_fence(__ATOMIC_RELEASE, "agent");
        __syncthreads();
        if (tid == 0)
            __hip_atomic_store(&flags[b], t + 1, __ATOMIC_RELAXED, __HIP_MEMORY_SCOPE_AGENT);

        // 7. off-critical-path: readout rows + register rotate
        float* Arow = Achunk + (long)(t - t0) * KTOT;
#pragma unroll
        for (int ry = 0; ry < 4; ++ry) {
            Arow[(y0 + ry) * DD + x] = Vn[ry];
            Arow[CELLS + (y0 + ry) * DD + x] = Sn[ry];
            V[ry] = Vn[ry];
        }
    }

    // save V for next chunk
#pragma unroll
    for (int ry = 0; ry < 4; ++ry) Vsave[(y0 + ry) * DD + x] = V[ry];
}

// Split-K fp32 GEMM on one chunk: 64 t x 128 o x KSLAB k per block. Grid (2, NSLAB).
__global__ __launch_bounds__(256) void gemm_partial(
    const float* __restrict__ A,   // chunk [TB][KTOT]
    const float* __restrict__ B,   // W_out [128][KTOT]
    float* __restrict__ P)         // [NSLAB][TB][128]
{
    __shared__ float As[16][68];   // [k][t]
    __shared__ float Bs[16][132];  // [k][o]
    const int tid = threadIdx.x;
    const int t0 = blockIdx.x * 64;
    const long k0 = (long)blockIdx.y * KSLAB;
    const int tx = tid & 15;       // 8 o's each
    const int ty = tid >> 4;       // 4 t's each

    float acc[4][8];
#pragma unroll
    for (int i = 0; i < 4; ++i)
#pragma unroll
        for (int j = 0; j < 8; ++j) acc[i][j] = 0.0f;

    const int ar = tid >> 2, ac = (tid & 3) * 4;   // A: 64 rows x 16 k
    const int br = tid >> 1, bc = (tid & 1) * 8;   // B: 128 rows x 16 k

    for (int kc = 0; kc < KSLAB; kc += 16) {
        float4 av = *(const float4*)&A[(long)(t0 + ar) * KTOT + k0 + kc + ac];
        As[ac+0][ar] = av.x; As[ac+1][ar] = av.y; As[ac+2][ar] = av.z; As[ac+3][ar] = av.w;
        float4 bv0 = *(const float4*)&B[(long)br * KTOT + k0 + kc + bc];
        float4 bv1 = *(const float4*)&B[(long)br * KTOT + k0 + kc + bc + 4];
        Bs[bc+0][br] = bv0.x; Bs[bc+1][br] = bv0.y; Bs[bc+2][br] = bv0.z; Bs[bc+3][br] = bv0.w;
        Bs[bc+4][br] = bv1.x; Bs[bc+5][br] = bv1.y; Bs[bc+6][br] = bv1.z; Bs[bc+7][br] = bv1.w;
        __syncthreads();
#pragma unroll
        for (int kk = 0; kk < 16; ++kk) {
            float4 a4  = *(const float4*)&As[kk][ty*4];
            float4 b40 = *(const float4*)&Bs[kk][tx*8];
            float4 b41 = *(const float4*)&Bs[kk][tx*8+4];
            float a[4] = {a4.x, a4.y, a4.z, a4.w};
            float b[8] = {b40.x, b40.y, b40.z, b40.w, b41.x, b41.y, b41.z, b41.w};
#pragma unroll
            for (int i = 0; i < 4; ++i)
#pragma unroll
                for (int j = 0; j < 8; ++j) acc[i][j] += a[i] * b[j];
        }
        __syncthreads();
    }
#pragma unroll
    for (int i = 0; i < 4; ++i)
#pragma unroll
        for (int j = 0; j < 8; ++j)
            P[((long)blockIdx.y * TB + t0 + ty*4 + i) * 128 + tx*8 + j] = acc[i][j];
}

// Sum NSLAB partials for one chunk, add bias, write out rows [c*TB, (c+1)*TB).
__global__ __launch_bounds__(256) void reduce_kernel(
    const float* __restrict__ P, const float* __restrict__ bias,
    float* __restrict__ out, int c)
{
    int tid = blockIdx.x * 256 + threadIdx.x;      // 16384 = TB*128
    int o = tid & 127;
    float acc = 0.0f;
#pragma unroll 8
    for (int j = 0; j < NSLAB; ++j) acc += P[(long)j * (TB * 128) + tid];
    out[(long)c * (TB * 128) + tid] = acc + bias[o];
}

} // namespace

extern "C" void kernel_launch(void* const* d_in, const int* in_sizes, int n_in,
                              void* d_out, int out_size, void* d_ws, size_t ws_size,
                              hipStream_t stream)
{
    const float* X  = (const float*)d_in[0];   // [512,1024]
    const float* We = (const float*)d_in[1];   // [1024,1024] permuted identity
    const float* mc = (const float*)d_in[2];   // [32,32]
    const float* mf = (const float*)d_in[3];   // [256,256]
    const float* Wo = (const float*)d_in[4];   // [128,2,256,256]
    const float* bo = (const float*)d_in[5];   // [128]
    float* out = (float*)d_out;                // [512,128] fp32

    if (ws_size < (size_t)WS_REQUIRED) return;  // fail loudly (wrong result, no fault)

    char* ws = (char*)d_ws;
    int*   perm   = (int*)(ws + OFF_PERM);
    int*   flags  = (int*)(ws + OFF_FLAG);
    float* Vsave  = (float*)(ws + OFF_VSAVE);
    float* Sst    = (float*)(ws + OFF_S);
    float* Achunk = (float*)(ws + OFF_A);
    float* P      = (float*)(ws + OFF_P);

    perm_kernel<<<4096, 256, 0, stream>>>(We, perm);
    for (int c = 0; c < NCH; ++c) {
        flags_init<<<1, 64, 0, stream>>>(flags, c * TB);
        scan_chunk<<<64, 256, 0, stream>>>(X, perm, mc, mf, Sst, Vsave, Achunk, flags, c * TB);
        gemm_partial<<<dim3(2, NSLAB), 256, 0, stream>>>(Achunk, Wo, P);
        reduce_kernel<<<64, 256, 0, stream>>>(P, bo, out, c);
    }
}

// Round 4
// 2240.759 us; speedup vs baseline: 2.2320x; 2.2320x over previous
//
#include <hip/hip_runtime.h>
#include <cstdint>

// Cortex reservoir: embed(perm-gather) -> single-XCD persistent neighbor-synced
// spiking scan -> chunked dense readout GEMM.
//
// Scan coherence design (gfx950, 8 XCDs): all 64 worker blocks are confined to
// XCD 0 (HW_REG_XCC_ID + ticket). Within one XCD the L2 is the coherence point,
// so per-step release = s_waitcnt vmcnt(0) (no buffer_wbl2) and acquire =
// buffer_inv (L1-only). Flags use agent-scope atomics (coherent at IC).
//
// ws layout (~73 MiB):
//   OFF_PERM  : perm int[1024]
//   OFF_FLAG  : flags int[64*16] (padded) + ticket at [1024]
//   OFF_VSAVE : V snapshot float[65536]
//   OFF_S     : S ping-pong float[2][65536]
//   OFF_A     : A chunk float[128][131072]
//   OFF_P     : split-K partials float[128][128][128]

namespace {

constexpr int TT = 512;
constexpr int DD = 256;
constexpr int CELLS = DD * DD;              // 65536
constexpr long KTOT = 2L * CELLS;           // 131072
constexpr int TB = 128;                     // time-chunk
constexpr int NCH = TT / TB;                // 4
constexpr int KSLAB = 1024;
constexpr int NSLAB = 128;                  // KTOT / KSLAB
constexpr int NW = 64;                      // worker blocks (one XCD)

constexpr long OFF_PERM = 0;
constexpr long OFF_FLAG = 4096;
constexpr long OFF_VSAVE = OFF_FLAG + 8192;
constexpr long OFF_S = OFF_VSAVE + (long)CELLS * 4;
constexpr long OFF_A = OFF_S + 2L * CELLS * 4;
constexpr long OFF_P = OFF_A + (long)TB * KTOT * 4;
constexpr long WS_REQUIRED = OFF_P + (long)NSLAB * TB * 128 * 4;  // ~72.8 MiB

__device__ __forceinline__ int xcc_id() {
    int x;
    asm volatile("s_getreg_b32 %0, hwreg(HW_REG_XCC_ID, 0, 4)" : "=s"(x));
    return x;
}

__global__ __launch_bounds__(256) void perm_kernel(const float* __restrict__ We,
                                                   int* __restrict__ perm) {
    int idx = blockIdx.x * 256 + threadIdx.x;       // over 1024*1024
    if (We[idx] > 0.5f) perm[idx >> 10] = idx & 1023;
}

__global__ void ctrl_init(int* __restrict__ flags, int v) {
    int i = threadIdx.x;
    if (i < NW) flags[i * 16] = v;
    if (i == NW) flags[1024] = 0;   // ticket counter
}

// Persistent scan for one 128-step chunk. 1024 blocks launched; 64 workers on
// XCD 0 (ticket-selected), each owns 4 rows. Block b at step t needs S_{t-1}
// from workers b+-1, b+-2 (circular, radius 8 = 2 strips).
__global__ __launch_bounds__(256) void scan_chunk(
    const float* __restrict__ X,
    const int* __restrict__ perm,
    const float* __restrict__ mc,
    const float* __restrict__ mf,
    float* __restrict__ Sst,      // ping-pong [2][CELLS]
    float* __restrict__ Vsave,    // [CELLS]
    float* __restrict__ Achunk,   // [TB][KTOT]
    int* __restrict__ flags,      // padded [64*16]; ticket at [1024]
    int t0)
{
#pragma clang fp contract(off)
    __shared__ float Sld[20][DD];   // rows y0-8 .. y0+11 of S_{t-1}
    __shared__ float C5[4][DD];     // vertical 5-sums
    __shared__ float C9[4][DD];     // vertical dilated 9-sums
    __shared__ float ut[32];        // per-step input drive (32 coarse cells)
    __shared__ int sh_b;
    __shared__ int sh_bail;

    const int tid = threadIdx.x;
    const int xcc = xcc_id();
    if (tid == 0) {
        int tk = -1;
        if (xcc == 0)
            tk = __hip_atomic_fetch_add(&flags[1024], 1, __ATOMIC_RELAXED,
                                        __HIP_MEMORY_SCOPE_AGENT);
        sh_b = tk;
    }
    __syncthreads();
    const int b = sh_b;
    if (b < 0 || b >= NW) return;   // uniform per block

    const int y0 = b * 4;           // 4-row strip, inside one coarse row
    const int cy = y0 >> 3;
    const int x = tid;
    const int nb0 = ((b + 62) & 63) * 16, nb1 = ((b + 63) & 63) * 16;
    const int nb2 = ((b + 1) & 63) * 16,  nb3 = ((b + 2) & 63) * 16;

    // V state lives in registers for the whole chunk.
    float V[4];
    if (t0 == 0) {
        V[0] = V[1] = V[2] = V[3] = 0.0f;
    } else {
#pragma unroll
        for (int ry = 0; ry < 4; ++ry) V[ry] = Vsave[(y0 + ry) * DD + x];
    }
    float mfv[4];
#pragma unroll
    for (int ry = 0; ry < 4; ++ry) mfv[ry] = mf[(y0 + ry) * DD + x];

    for (int t = t0; t < t0 + TB; ++t) {
        // 1. wait for neighbors to publish S_{t-1} (flag == completed steps)
        if (tid == 0) {
            long g = 0; int bail = 0;
            while (__hip_atomic_load(&flags[nb0], __ATOMIC_RELAXED, __HIP_MEMORY_SCOPE_AGENT) < t) { if (++g > (1L << 22)) { bail = 1; break; } }
            while (!bail && __hip_atomic_load(&flags[nb1], __ATOMIC_RELAXED, __HIP_MEMORY_SCOPE_AGENT) < t) { if (++g > (1L << 23)) { bail = 1; break; } }
            while (!bail && __hip_atomic_load(&flags[nb2], __ATOMIC_RELAXED, __HIP_MEMORY_SCOPE_AGENT) < t) { if (++g > (1L << 24)) { bail = 1; break; } }
            while (!bail && __hip_atomic_load(&flags[nb3], __ATOMIC_RELAXED, __HIP_MEMORY_SCOPE_AGENT) < t) { if (++g > (1L << 24)) { bail = 1; break; } }
            sh_bail = bail;
            if (bail)   // let neighbors terminate too, then abandon chunk
                __hip_atomic_store(&flags[b * 16], t0 + TB, __ATOMIC_RELAXED,
                                   __HIP_MEMORY_SCOPE_AGENT);
        }
        __syncthreads();
        if (sh_bail) break;
        // acquire within XCD: drop stale L1 lines; shared L2 is authoritative
        asm volatile("buffer_inv" ::: "memory");

        // 2. input drive for this step (exact: mc in {0,1})
        if (tid < 32) {
            int c = cy * 32 + tid;
            ut[tid] = tanhf(X[(long)t * 1024 + perm[c]] * mc[c]);
        }

        // 3. halo load: 20 rows of S_{t-1} (slot (t+1)&1)
        const float* Sprev = Sst + (long)((t + 1) & 1) * CELLS;
        for (int i = tid; i < 20 * 64; i += 256) {
            int rr = i >> 6;
            int x4 = (i & 63) << 2;
            float4 s = make_float4(0.f, 0.f, 0.f, 0.f);
            if (t > 0) {
                int gy = (y0 - 8 + rr) & 255;
                s = *(const float4*)&Sprev[gy * DD + x4];
            }
            *(float4*)&Sld[rr][x4] = s;
        }
        __syncthreads();

        // 4. vertical sums (exact integer counts in fp32)
#pragma unroll
        for (int ry = 0; ry < 4; ++ry) {
            int r = 8 + ry;
            C5[ry][x] = Sld[r-2][x] + Sld[r-1][x] + Sld[r][x] + Sld[r+1][x] + Sld[r+2][x];
            C9[ry][x] = Sld[r-8][x] + Sld[r-6][x] + Sld[r-4][x] + Sld[r-2][x] + Sld[r][x]
                      + Sld[r+2][x] + Sld[r+4][x] + Sld[r+6][x] + Sld[r+8][x];
        }
        __syncthreads();

        // 5. horizontal sums + V update (V in regs)
        float Vn[4], Sn[4];
        const float um = ut[x >> 3];
#pragma unroll
        for (int ry = 0; ry < 4; ++ry) {
            float h5 = C5[ry][(x-2)&255] + C5[ry][(x-1)&255] + C5[ry][x]
                     + C5[ry][(x+1)&255] + C5[ry][(x+2)&255];
            float h9 = C9[ry][(x-8)&255] + C9[ry][(x-6)&255] + C9[ry][(x-4)&255]
                     + C9[ry][(x-2)&255] + C9[ry][x]
                     + C9[ry][(x+2)&255] + C9[ry][(x+4)&255]
                     + C9[ry][(x+6)&255] + C9[ry][(x+8)&255];
            float avg5 = h5 * (1.0f/25.0f);
            float avg9 = h9 * (1.0f/81.0f);
            float lat = avg5 - 0.5f * avg9;          // EXC*avg5 + INH*avg9
            float u = um * mfv[ry];                  // exact: mf in {0,1}
            float V1 = 0.9f * V[ry] + 0.5f * u;      // DECAY*V + SPLIT*x
            float V2 = (V1 >= 0.1f) ? ((V1 + 0.5f * u) + lat) : V1;
            V2 = fminf(V2, 1.0f);
            const bool sp = V2 > 0.75f;
            Vn[ry] = sp ? 0.0f : V2;
            Sn[ry] = sp ? 1.0f : 0.0f;
        }
        float* Scur = Sst + (long)(t & 1) * CELLS;
#pragma unroll
        for (int ry = 0; ry < 4; ++ry) Scur[(y0 + ry) * DD + x] = Sn[ry];

        // 6. release within XCD: drain own stores to the shared L2, then flag.
        asm volatile("s_waitcnt vmcnt(0)" ::: "memory");
        __syncthreads();                 // all waves drained
        if (tid == 0)
            __hip_atomic_store(&flags[b * 16], t + 1, __ATOMIC_RELAXED,
                               __HIP_MEMORY_SCOPE_AGENT);

        // 7. off-critical-path: readout rows + register rotate
        float* Arow = Achunk + (long)(t - t0) * KTOT;
#pragma unroll
        for (int ry = 0; ry < 4; ++ry) {
            Arow[(y0 + ry) * DD + x] = Vn[ry];
            Arow[CELLS + (y0 + ry) * DD + x] = Sn[ry];
            V[ry] = Vn[ry];
        }
    }

    // save V for next chunk
#pragma unroll
    for (int ry = 0; ry < 4; ++ry) Vsave[(y0 + ry) * DD + x] = V[ry];
}

// Split-K fp32 GEMM on one chunk: 64 t x 128 o x KSLAB k per block. Grid (2, NSLAB).
__global__ __launch_bounds__(256) void gemm_partial(
    const float* __restrict__ A,   // chunk [TB][KTOT]
    const float* __restrict__ B,   // W_out [128][KTOT]
    float* __restrict__ P)         // [NSLAB][TB][128]
{
    __shared__ float As[16][68];   // [k][t]
    __shared__ float Bs[16][132];  // [k][o]
    const int tid = threadIdx.x;
    const int t0 = blockIdx.x * 64;
    const long k0 = (long)blockIdx.y * KSLAB;
    const int tx = tid & 15;       // 8 o's each
    const int ty = tid >> 4;       // 4 t's each

    float acc[4][8];
#pragma unroll
    for (int i = 0; i < 4; ++i)
#pragma unroll
        for (int j = 0; j < 8; ++j) acc[i][j] = 0.0f;

    const int ar = tid >> 2, ac = (tid & 3) * 4;   // A: 64 rows x 16 k
    const int br = tid >> 1, bc = (tid & 1) * 8;   // B: 128 rows x 16 k

    for (int kc = 0; kc < KSLAB; kc += 16) {
        float4 av = *(const float4*)&A[(long)(t0 + ar) * KTOT + k0 + kc + ac];
        As[ac+0][ar] = av.x; As[ac+1][ar] = av.y; As[ac+2][ar] = av.z; As[ac+3][ar] = av.w;
        float4 bv0 = *(const float4*)&B[(long)br * KTOT + k0 + kc + bc];
        float4 bv1 = *(const float4*)&B[(long)br * KTOT + k0 + kc + bc + 4];
        Bs[bc+0][br] = bv0.x; Bs[bc+1][br] = bv0.y; Bs[bc+2][br] = bv0.z; Bs[bc+3][br] = bv0.w;
        Bs[bc+4][br] = bv1.x; Bs[bc+5][br] = bv1.y; Bs[bc+6][br] = bv1.z; Bs[bc+7][br] = bv1.w;
        __syncthreads();
#pragma unroll
        for (int kk = 0; kk < 16; ++kk) {
            float4 a4  = *(const float4*)&As[kk][ty*4];
            float4 b40 = *(const float4*)&Bs[kk][tx*8];
            float4 b41 = *(const float4*)&Bs[kk][tx*8+4];
            float a[4] = {a4.x, a4.y, a4.z, a4.w};
            float b[8] = {b40.x, b40.y, b40.z, b40.w, b41.x, b41.y, b41.z, b41.w};
#pragma unroll
            for (int i = 0; i < 4; ++i)
#pragma unroll
                for (int j = 0; j < 8; ++j) acc[i][j] += a[i] * b[j];
        }
        __syncthreads();
    }
#pragma unroll
    for (int i = 0; i < 4; ++i)
#pragma unroll
        for (int j = 0; j < 8; ++j)
            P[((long)blockIdx.y * TB + t0 + ty*4 + i) * 128 + tx*8 + j] = acc[i][j];
}

// Sum NSLAB partials for one chunk, add bias, write out rows [c*TB, (c+1)*TB).
__global__ __launch_bounds__(256) void reduce_kernel(
    const float* __restrict__ P, const float* __restrict__ bias,
    float* __restrict__ out, int c)
{
    int tid = blockIdx.x * 256 + threadIdx.x;      // 16384 = TB*128
    int o = tid & 127;
    float acc = 0.0f;
#pragma unroll 8
    for (int j = 0; j < NSLAB; ++j) acc += P[(long)j * (TB * 128) + tid];
    out[(long)c * (TB * 128) + tid] = acc + bias[o];
}

} // namespace

extern "C" void kernel_launch(void* const* d_in, const int* in_sizes, int n_in,
                              void* d_out, int out_size, void* d_ws, size_t ws_size,
                              hipStream_t stream)
{
    const float* X  = (const float*)d_in[0];   // [512,1024]
    const float* We = (const float*)d_in[1];   // [1024,1024] permuted identity
    const float* mc = (const float*)d_in[2];   // [32,32]
    const float* mf = (const float*)d_in[3];   // [256,256]
    const float* Wo = (const float*)d_in[4];   // [128,2,256,256]
    const float* bo = (const float*)d_in[5];   // [128]
    float* out = (float*)d_out;                // [512,128] fp32

    if (ws_size < (size_t)WS_REQUIRED) return;  // fail loudly (wrong result, no fault)

    char* ws = (char*)d_ws;
    int*   perm   = (int*)(ws + OFF_PERM);
    int*   flags  = (int*)(ws + OFF_FLAG);
    float* Vsave  = (float*)(ws + OFF_VSAVE);
    float* Sst    = (float*)(ws + OFF_S);
    float* Achunk = (float*)(ws + OFF_A);
    float* P      = (float*)(ws + OFF_P);

    perm_kernel<<<4096, 256, 0, stream>>>(We, perm);
    for (int c = 0; c < NCH; ++c) {
        ctrl_init<<<1, 128, 0, stream>>>(flags, c * TB);
        scan_chunk<<<1024, 256, 0, stream>>>(X, perm, mc, mf, Sst, Vsave, Achunk,
                                             flags, c * TB);
        gemm_partial<<<dim3(2, NSLAB), 256, 0, stream>>>(Achunk, Wo, P);
        reduce_kernel<<<64, 256, 0, stream>>>(P, bo, out, c);
    }
}

// Round 5
// 2104.482 us; speedup vs baseline: 2.3766x; 1.0648x over previous
//
#include <hip/hip_runtime.h>
#include <cstdint>

// Cortex reservoir: embed(perm-gather) -> single-XCD persistent neighbor-synced
// spiking scan -> chunked dense readout GEMM.
//
// Scan coherence design (gfx950, 8 XCDs): all 64 worker blocks are confined to
// XCD 0 (HW_REG_XCC_ID + ticket). Within one XCD the L2 is the coherence point:
//   release = s_waitcnt vmcnt(0) (stores reach write-through L2), then plain flag store
//   acquire = volatile flag load with buffer_inv (L1-only invalidate) in the poll loop
// Flags are plain L2-coherent ints (no sc1 / Infinity-Cache round-trips).
//
// ws layout (~73 MiB):
//   OFF_PERM  : perm int[1024]
//   OFF_FLAG  : flags int[64*16] (padded) + ticket at [1024]
//   OFF_VSAVE : V snapshot float[65536]
//   OFF_S     : S ping-pong float[2][65536]
//   OFF_A     : A chunk float[128][131072]
//   OFF_P     : split-K partials float[128][128][128]

namespace {

constexpr int TT = 512;
constexpr int DD = 256;
constexpr int CELLS = DD * DD;              // 65536
constexpr long KTOT = 2L * CELLS;           // 131072
constexpr int TB = 128;                     // time-chunk
constexpr int NCH = TT / TB;                // 4
constexpr int KSLAB = 1024;
constexpr int NSLAB = 128;                  // KTOT / KSLAB
constexpr int NW = 64;                      // worker blocks (one XCD)

constexpr long OFF_PERM = 0;
constexpr long OFF_FLAG = 4096;
constexpr long OFF_VSAVE = OFF_FLAG + 8192;
constexpr long OFF_S = OFF_VSAVE + (long)CELLS * 4;
constexpr long OFF_A = OFF_S + 2L * CELLS * 4;
constexpr long OFF_P = OFF_A + (long)TB * KTOT * 4;
constexpr long WS_REQUIRED = OFF_P + (long)NSLAB * TB * 128 * 4;  // ~72.8 MiB

__device__ __forceinline__ int xcc_id() {
    int x;
    asm volatile("s_getreg_b32 %0, hwreg(HW_REG_XCC_ID, 0, 4)" : "=s"(x));
    return x;
}

__global__ __launch_bounds__(256) void perm_kernel(const float* __restrict__ We,
                                                   int* __restrict__ perm) {
    int idx = blockIdx.x * 256 + threadIdx.x;       // over 1024*1024
    if (We[idx] > 0.5f) perm[idx >> 10] = idx & 1023;
}

__global__ void ctrl_init(int* __restrict__ flags, int v) {
    int i = threadIdx.x;
    if (i < NW) flags[i * 16] = v;
    if (i == NW) flags[1024] = 0;   // ticket counter
}

// Persistent scan for one 128-step chunk. 1024 blocks launched; 64 workers on
// XCD 0 (ticket-selected), each owns 4 rows. Block b at step t needs S_{t-1}
// from workers b+-1, b+-2 (circular, radius 8 = 2 strips).
__global__ __launch_bounds__(256) void scan_chunk(
    const float* __restrict__ X,
    const int* __restrict__ perm,
    const float* __restrict__ mc,
    const float* __restrict__ mf,
    float* __restrict__ Sst,      // ping-pong [2][CELLS]
    float* __restrict__ Vsave,    // [CELLS]
    float* __restrict__ Achunk,   // [TB][KTOT]
    int* __restrict__ flags,      // padded [64*16]; ticket at [1024]
    int t0)
{
#pragma clang fp contract(off)
    __shared__ float Sld[20][DD];   // rows y0-8 .. y0+11 of S_{t-1}
    __shared__ float C5[4][DD];     // vertical 5-sums
    __shared__ float C9[4][DD];     // vertical dilated 9-sums
    __shared__ float ut[32];        // per-step input drive (32 coarse cells)
    __shared__ int sh_b;
    __shared__ int sh_bail;

    const int tid = threadIdx.x;
    const int xcc = xcc_id();
    if (tid == 0) {
        int tk = -1;
        if (xcc == 0)
            tk = __hip_atomic_fetch_add(&flags[1024], 1, __ATOMIC_RELAXED,
                                        __HIP_MEMORY_SCOPE_AGENT);
        sh_b = tk;
        sh_bail = 0;
    }
    __syncthreads();
    const int b = sh_b;
    if (b < 0 || b >= NW) return;   // uniform per block

    const int y0 = b * 4;           // 4-row strip, inside one coarse row
    const int cy = y0 >> 3;
    const int x = tid;
    // neighbor flag slot for this polling thread (tid 0..3)
    const int nbi = (tid == 0) ? ((b + 62) & 63) : (tid == 1) ? ((b + 63) & 63)
                  : (tid == 2) ? ((b + 1) & 63)  : ((b + 2) & 63);
    volatile int* nbf = (volatile int*)&flags[nbi * 16];
    volatile int* myf = (volatile int*)&flags[b * 16];

    // V state lives in registers for the whole chunk.
    float V[4];
    if (t0 == 0) {
        V[0] = V[1] = V[2] = V[3] = 0.0f;
    } else {
#pragma unroll
        for (int ry = 0; ry < 4; ++ry) V[ry] = Vsave[(y0 + ry) * DD + x];
    }
    float mfv[4];
#pragma unroll
    for (int ry = 0; ry < 4; ++ry) mfv[ry] = mf[(y0 + ry) * DD + x];

    for (int t = t0; t < t0 + TB; ++t) {
        // 1. wait for neighbors to publish S_{t-1} (flag == completed steps).
        //    Threads 0..3 poll one neighbor each, in parallel, at L2.
        if (tid < 4) {
            long g = 0;
            while (*nbf < t) {
                asm volatile("buffer_inv" ::: "memory");  // drop stale L1 lines
                if (++g > (1L << 22)) { sh_bail = 1; break; }
            }
        }
        __syncthreads();
        if (sh_bail) {              // let neighbors terminate too, then abandon
            if (tid == 0) *myf = t0 + TB;
            break;
        }
        // acquire within XCD: drop stale L1 lines; shared L2 is authoritative
        asm volatile("buffer_inv" ::: "memory");

        // 2. input drive for this step (exact: mc in {0,1})
        if (tid < 32) {
            int c = cy * 32 + tid;
            ut[tid] = tanhf(X[(long)t * 1024 + perm[c]] * mc[c]);
        }

        // 3. halo load: 20 rows of S_{t-1} (slot (t+1)&1)
        const float* Sprev = Sst + (long)((t + 1) & 1) * CELLS;
        for (int i = tid; i < 20 * 64; i += 256) {
            int rr = i >> 6;
            int x4 = (i & 63) << 2;
            float4 s = make_float4(0.f, 0.f, 0.f, 0.f);
            if (t > 0) {
                int gy = (y0 - 8 + rr) & 255;
                s = *(const float4*)&Sprev[gy * DD + x4];
            }
            *(float4*)&Sld[rr][x4] = s;
        }
        __syncthreads();

        // 4. vertical sums (exact integer counts in fp32)
#pragma unroll
        for (int ry = 0; ry < 4; ++ry) {
            int r = 8 + ry;
            C5[ry][x] = Sld[r-2][x] + Sld[r-1][x] + Sld[r][x] + Sld[r+1][x] + Sld[r+2][x];
            C9[ry][x] = Sld[r-8][x] + Sld[r-6][x] + Sld[r-4][x] + Sld[r-2][x] + Sld[r][x]
                      + Sld[r+2][x] + Sld[r+4][x] + Sld[r+6][x] + Sld[r+8][x];
        }
        __syncthreads();

        // 5. horizontal sums + V update (V in regs)
        float Vn[4], Sn[4];
        const float um = ut[x >> 3];
#pragma unroll
        for (int ry = 0; ry < 4; ++ry) {
            float h5 = C5[ry][(x-2)&255] + C5[ry][(x-1)&255] + C5[ry][x]
                     + C5[ry][(x+1)&255] + C5[ry][(x+2)&255];
            float h9 = C9[ry][(x-8)&255] + C9[ry][(x-6)&255] + C9[ry][(x-4)&255]
                     + C9[ry][(x-2)&255] + C9[ry][x]
                     + C9[ry][(x+2)&255] + C9[ry][(x+4)&255]
                     + C9[ry][(x+6)&255] + C9[ry][(x+8)&255];
            float avg5 = h5 * (1.0f/25.0f);
            float avg9 = h9 * (1.0f/81.0f);
            float lat = avg5 - 0.5f * avg9;          // EXC*avg5 + INH*avg9
            float u = um * mfv[ry];                  // exact: mf in {0,1}
            float V1 = 0.9f * V[ry] + 0.5f * u;      // DECAY*V + SPLIT*x
            float V2 = (V1 >= 0.1f) ? ((V1 + 0.5f * u) + lat) : V1;
            V2 = fminf(V2, 1.0f);
            const bool sp = V2 > 0.75f;
            Vn[ry] = sp ? 0.0f : V2;
            Sn[ry] = sp ? 1.0f : 0.0f;
        }
        float* Scur = Sst + (long)(t & 1) * CELLS;
#pragma unroll
        for (int ry = 0; ry < 4; ++ry) Scur[(y0 + ry) * DD + x] = Sn[ry];

        // 6. release within XCD: drain own stores to the write-through L2, flag.
        asm volatile("s_waitcnt vmcnt(0)" ::: "memory");
        __syncthreads();                 // all waves drained
        if (tid == 0) *myf = t + 1;      // plain store -> L2 (flag slot)

        // 7. off-critical-path: readout rows + register rotate
        float* Arow = Achunk + (long)(t - t0) * KTOT;
#pragma unroll
        for (int ry = 0; ry < 4; ++ry) {
            Arow[(y0 + ry) * DD + x] = Vn[ry];
            Arow[CELLS + (y0 + ry) * DD + x] = Sn[ry];
            V[ry] = Vn[ry];
        }
    }

    // save V for next chunk
#pragma unroll
    for (int ry = 0; ry < 4; ++ry) Vsave[(y0 + ry) * DD + x] = V[ry];
}

// Split-K fp32 GEMM on one chunk: 64 t x 128 o x KSLAB k per block. Grid (2, NSLAB).
__global__ __launch_bounds__(256) void gemm_partial(
    const float* __restrict__ A,   // chunk [TB][KTOT]
    const float* __restrict__ B,   // W_out [128][KTOT]
    float* __restrict__ P)         // [NSLAB][TB][128]
{
    __shared__ float As[16][68];   // [k][t]
    __shared__ float Bs[16][132];  // [k][o]
    const int tid = threadIdx.x;
    const int t0 = blockIdx.x * 64;
    const long k0 = (long)blockIdx.y * KSLAB;
    const int tx = tid & 15;       // 8 o's each
    const int ty = tid >> 4;       // 4 t's each

    float acc[4][8];
#pragma unroll
    for (int i = 0; i < 4; ++i)
#pragma unroll
        for (int j = 0; j < 8; ++j) acc[i][j] = 0.0f;

    const int ar = tid >> 2, ac = (tid & 3) * 4;   // A: 64 rows x 16 k
    const int br = tid >> 1, bc = (tid & 1) * 8;   // B: 128 rows x 16 k

    for (int kc = 0; kc < KSLAB; kc += 16) {
        float4 av = *(const float4*)&A[(long)(t0 + ar) * KTOT + k0 + kc + ac];
        As[ac+0][ar] = av.x; As[ac+1][ar] = av.y; As[ac+2][ar] = av.z; As[ac+3][ar] = av.w;
        float4 bv0 = *(const float4*)&B[(long)br * KTOT + k0 + kc + bc];
        float4 bv1 = *(const float4*)&B[(long)br * KTOT + k0 + kc + bc + 4];
        Bs[bc+0][br] = bv0.x; Bs[bc+1][br] = bv0.y; Bs[bc+2][br] = bv0.z; Bs[bc+3][br] = bv0.w;
        Bs[bc+4][br] = bv1.x; Bs[bc+5][br] = bv1.y; Bs[bc+6][br] = bv1.z; Bs[bc+7][br] = bv1.w;
        __syncthreads();
#pragma unroll
        for (int kk = 0; kk < 16; ++kk) {
            float4 a4  = *(const float4*)&As[kk][ty*4];
            float4 b40 = *(const float4*)&Bs[kk][tx*8];
            float4 b41 = *(const float4*)&Bs[kk][tx*8+4];
            float a[4] = {a4.x, a4.y, a4.z, a4.w};
            float b[8] = {b40.x, b40.y, b40.z, b40.w, b41.x, b41.y, b41.z, b41.w};
#pragma unroll
            for (int i = 0; i < 4; ++i)
#pragma unroll
                for (int j = 0; j < 8; ++j) acc[i][j] += a[i] * b[j];
        }
        __syncthreads();
    }
#pragma unroll
    for (int i = 0; i < 4; ++i)
#pragma unroll
        for (int j = 0; j < 8; ++j)
            P[((long)blockIdx.y * TB + t0 + ty*4 + i) * 128 + tx*8 + j] = acc[i][j];
}

// Sum NSLAB partials for one chunk, add bias, write out rows [c*TB, (c+1)*TB).
__global__ __launch_bounds__(256) void reduce_kernel(
    const float* __restrict__ P, const float* __restrict__ bias,
    float* __restrict__ out, int c)
{
    int tid = blockIdx.x * 256 + threadIdx.x;      // 16384 = TB*128
    int o = tid & 127;
    float acc = 0.0f;
#pragma unroll 8
    for (int j = 0; j < NSLAB; ++j) acc += P[(long)j * (TB * 128) + tid];
    out[(long)c * (TB * 128) + tid] = acc + bias[o];
}

} // namespace

extern "C" void kernel_launch(void* const* d_in, const int* in_sizes, int n_in,
                              void* d_out, int out_size, void* d_ws, size_t ws_size,
                              hipStream_t stream)
{
    const float* X  = (const float*)d_in[0];   // [512,1024]
    const float* We = (const float*)d_in[1];   // [1024,1024] permuted identity
    const float* mc = (const float*)d_in[2];   // [32,32]
    const float* mf = (const float*)d_in[3];   // [256,256]
    const float* Wo = (const float*)d_in[4];   // [128,2,256,256]
    const float* bo = (const float*)d_in[5];   // [128]
    float* out = (float*)d_out;                // [512,128] fp32

    if (ws_size < (size_t)WS_REQUIRED) return;  // fail loudly (wrong result, no fault)

    char* ws = (char*)d_ws;
    int*   perm   = (int*)(ws + OFF_PERM);
    int*   flags  = (int*)(ws + OFF_FLAG);
    float* Vsave  = (float*)(ws + OFF_VSAVE);
    float* Sst    = (float*)(ws + OFF_S);
    float* Achunk = (float*)(ws + OFF_A);
    float* P      = (float*)(ws + OFF_P);

    perm_kernel<<<4096, 256, 0, stream>>>(We, perm);
    for (int c = 0; c < NCH; ++c) {
        ctrl_init<<<1, 128, 0, stream>>>(flags, c * TB);
        scan_chunk<<<1024, 256, 0, stream>>>(X, perm, mc, mf, Sst, Vsave, Achunk,
                                             flags, c * TB);
        gemm_partial<<<dim3(2, NSLAB), 256, 0, stream>>>(Achunk, Wo, P);
        reduce_kernel<<<64, 256, 0, stream>>>(P, bo, out, c);
    }
}